// Round 1
// baseline (1506.922 us; speedup 1.0000x reference)
//
#include <hip/hip_runtime.h>
#include <hip/hip_bf16.h>
#include <stdint.h>

typedef __attribute__((ext_vector_type(4))) float  f32x4;
typedef __attribute__((ext_vector_type(4))) float  float4v;
typedef __attribute__((ext_vector_type(8))) short  short8v;
typedef __attribute__((ext_vector_type(4))) short  short4v;
typedef __attribute__((ext_vector_type(8))) unsigned short ushort8v;
typedef __attribute__((ext_vector_type(4))) unsigned short ushort4v;

#define B_   8
#define N_   2048
#define DIN  1024
#define H_   4
#define DH   256
#define QSZ  (B_ * H_ * N_ * DH)   // 16,777,216 elements per tensor

__device__ __forceinline__ unsigned short f2bf(float x) {
  union { float f; unsigned u; } v; v.f = x;
  unsigned r = v.u + 0x7fffu + ((v.u >> 16) & 1u);   // RNE
  return (unsigned short)(r >> 16);
}

__device__ __forceinline__ short8v pack8(short4v lo, short4v hi) {
  short8v r;
  r[0] = lo[0]; r[1] = lo[1]; r[2] = lo[2]; r[3] = lo[3];
  r[4] = hi[0]; r[5] = hi[1]; r[6] = hi[2]; r[7] = hi[3];
  return r;
}

// ---------------------------------------------------------------------------
// Kernel 1: QKV projection.  C[m, col] over col in [0,3072): Wq|Wk|Wv.
// 128x128 tile, BK=32, 4 waves (each 64x64).  Output bf16 in [B,H,N,DH],
// Q scaled by 1/16.
// ---------------------------------------------------------------------------
__global__ __launch_bounds__(256) void qkv_gemm(
    const float* __restrict__ x,
    const float* __restrict__ Wq, const float* __restrict__ bq,
    const float* __restrict__ Wk, const float* __restrict__ bk,
    const float* __restrict__ Wv, const float* __restrict__ bv,
    unsigned short* __restrict__ qkv)
{
  __shared__ __align__(16) unsigned short At[128][40];  // [m][k], pad 32->40
  __shared__ __align__(16) unsigned short Bt[128][40];  // [n][k] (W transposed)
  const int tid = threadIdx.x;
  const int lane = tid & 63, wid = tid >> 6;
  const int l15 = lane & 15, l4 = lane >> 4;
  const int m0 = blockIdx.x * 128;
  const int bc = blockIdx.y;                 // 0..23
  const int wsel = bc >> 3;                  // 0=Q 1=K 2=V
  const int c0 = (bc & 7) * 128;             // col within the 1024-wide W
  const float* W    = (wsel == 0) ? Wq : (wsel == 1) ? Wk : Wv;
  const float* bias = (wsel == 0) ? bq : (wsel == 1) ? bk : bv;
  const int wm = (wid >> 1) * 64, wn = (wid & 1) * 64;

  f32x4 acc[4][4] = {};

  for (int kt = 0; kt < DIN; kt += 32) {
    // stage A: x[m0..+128][kt..+32] fp32 -> bf16
    #pragma unroll
    for (int c = 0; c < 4; ++c) {
      int idx = c * 256 + tid;
      int r = idx >> 3, k4 = (idx & 7) << 2;
      float4v xv = *(const float4v*)(x + (size_t)(m0 + r) * DIN + kt + k4);
      ushort4v h;
      h[0] = f2bf(xv[0]); h[1] = f2bf(xv[1]); h[2] = f2bf(xv[2]); h[3] = f2bf(xv[3]);
      *(ushort4v*)&At[r][k4] = h;
    }
    // stage B transposed: W[kt..+32][c0..+128] -> Bt[n][k]
    #pragma unroll
    for (int c = 0; c < 4; ++c) {
      int idx = c * 256 + tid;
      int kr = idx >> 5, n4 = (idx & 31) << 2;
      float4v wv = *(const float4v*)(W + (size_t)(kt + kr) * 1024 + c0 + n4);
      Bt[n4 + 0][kr] = f2bf(wv[0]);
      Bt[n4 + 1][kr] = f2bf(wv[1]);
      Bt[n4 + 2][kr] = f2bf(wv[2]);
      Bt[n4 + 3][kr] = f2bf(wv[3]);
    }
    __syncthreads();

    short8v a[4], b[4];
    #pragma unroll
    for (int mf = 0; mf < 4; ++mf) {
      int r = wm + mf * 16 + l15, kk = l4 * 4;
      short4v lo = *(const short4v*)&At[r][kk];
      short4v hi = *(const short4v*)&At[r][kk + 16];
      a[mf] = pack8(lo, hi);
    }
    #pragma unroll
    for (int nf = 0; nf < 4; ++nf) {
      int r = wn + nf * 16 + l15, kk = l4 * 4;
      short4v lo = *(const short4v*)&Bt[r][kk];
      short4v hi = *(const short4v*)&Bt[r][kk + 16];
      b[nf] = pack8(lo, hi);
    }
    #pragma unroll
    for (int mf = 0; mf < 4; ++mf)
      #pragma unroll
      for (int nf = 0; nf < 4; ++nf)
        acc[mf][nf] = __builtin_amdgcn_mfma_f32_16x16x32_bf16(a[mf], b[nf], acc[mf][nf], 0, 0, 0);
    __syncthreads();
  }

  const float scale = (wsel == 0) ? 0.0625f : 1.0f;   // fold 1/sqrt(DH) into Q
  unsigned short* dst = qkv + (size_t)wsel * QSZ;
  #pragma unroll
  for (int nf = 0; nf < 4; ++nf) {
    int ncol = c0 + wn + nf * 16 + l15;      // in [0,1024)
    float bv_ = bias[ncol];
    int h = ncol >> 8, d = ncol & 255;
    #pragma unroll
    for (int mf = 0; mf < 4; ++mf) {
      #pragma unroll
      for (int e = 0; e < 4; ++e) {
        int mrow = m0 + wm + mf * 16 + l4 * 4 + e;
        int bb = mrow >> 11, n = mrow & 2047;
        float val = (acc[mf][nf][e] + bv_) * scale;
        dst[((size_t)(bb * H_ + h) * N_ + n) * DH + d] = f2bf(val);
      }
    }
  }
}

// ---------------------------------------------------------------------------
// Kernel 2: flash attention, swapped-operand form.
// Block = 4 waves, 64 q-rows (16 per wave); KV tile = 64.
// S^T = mfma(K_frag, Q_frag): lane owns q = lane&15 -> in-lane softmax.
// P stays in registers (S^T C/D layout == B-operand k-half layout).
// V staged in [dc=16][kv=64][dcol=16] subtiles, read via ds_read_b64_tr_b16.
// ---------------------------------------------------------------------------
__global__ __launch_bounds__(256) void attn_fused(
    const unsigned short* __restrict__ qkv,
    unsigned short* __restrict__ attn)
{
  __shared__ __align__(16) unsigned short Ks[16384];  // [dc][kv][dcol] subtiled
  __shared__ __align__(16) unsigned short Vs[16384];  // same layout
  const int tid = threadIdx.x;
  const int lane = tid & 63, wid = tid >> 6;
  const int l15 = lane & 15, l4 = lane >> 4;
  const int qt = blockIdx.x, bh = blockIdx.y;
  const unsigned short* Qh = qkv +                 (size_t)bh * N_ * DH;
  const unsigned short* Kh = qkv + (size_t)QSZ   + (size_t)bh * N_ * DH;
  const unsigned short* Vh = qkv + (size_t)2*QSZ + (size_t)bh * N_ * DH;

  // Q fragments in registers: wave's 16 q-rows, all 256 d (8 k-steps)
  const int q0 = qt * 64 + wid * 16;
  short8v qf[8];
  #pragma unroll
  for (int ks = 0; ks < 8; ++ks) {
    int d0 = ks * 32 + l4 * 4;
    short4v lo = *(const short4v*)(Qh + (size_t)(q0 + l15) * DH + d0);
    short4v hi = *(const short4v*)(Qh + (size_t)(q0 + l15) * DH + d0 + 16);
    qf[ks] = pack8(lo, hi);
  }

  f32x4 ot[16] = {};                 // O^T frags: d = df*16 + l4*4 + e, q = l15
  float m_run = -3.0e38f, l_run = 0.0f;
  const unsigned vbase = (unsigned)(uintptr_t)(&Vs[0]) + lane * 8;

  for (int t = 0; t < N_ / 64; ++t) {
    const int kv0 = t * 64;
    // stage K and V into 16-wide subtiles: elem = (d>>4)*1024 + kv*16 + (d&15)
    #pragma unroll
    for (int c = 0; c < 8; ++c) {
      int idx = c * 256 + tid;
      int r = idx >> 5, d0 = (idx & 31) * 8;
      int ldsoff = (d0 >> 4) * 1024 + r * 16 + (d0 & 15);
      *(ushort8v*)&Ks[ldsoff] = *(const ushort8v*)(Kh + (size_t)(kv0 + r) * DH + d0);
      *(ushort8v*)&Vs[ldsoff] = *(const ushort8v*)(Vh + (size_t)(kv0 + r) * DH + d0);
    }
    __syncthreads();

    // S^T[kv][q] = K . Q^T ; frag kf covers kv = kf*16 + l4*4 + e, q = l15
    f32x4 st[4];
    #pragma unroll
    for (int kf = 0; kf < 4; ++kf) {
      f32x4 s = {0.f, 0.f, 0.f, 0.f};
      #pragma unroll
      for (int ks = 0; ks < 8; ++ks) {
        int off = ks * 2048 + (kf * 16 + l15) * 16 + l4 * 4;
        short4v lo = *(const short4v*)&Ks[off];
        short4v hi = *(const short4v*)&Ks[off + 1024];
        s = __builtin_amdgcn_mfma_f32_16x16x32_bf16(pack8(lo, hi), qf[ks], s, 0, 0, 0);
      }
      st[kf] = s;
    }

    // online softmax: lane owns q = l15 (replicated over l4 groups)
    float tmax = -3.0e38f;
    #pragma unroll
    for (int kf = 0; kf < 4; ++kf)
      #pragma unroll
      for (int e = 0; e < 4; ++e) tmax = fmaxf(tmax, st[kf][e]);
    tmax = fmaxf(tmax, __shfl_xor(tmax, 16));
    tmax = fmaxf(tmax, __shfl_xor(tmax, 32));
    float mnew  = fmaxf(m_run, tmax);
    float alpha = __expf(m_run - mnew);
    float psum = 0.f;
    #pragma unroll
    for (int kf = 0; kf < 4; ++kf)
      #pragma unroll
      for (int e = 0; e < 4; ++e) {
        float p = __expf(st[kf][e] - mnew);
        st[kf][e] = p; psum += p;
      }
    psum += __shfl_xor(psum, 16);
    psum += __shfl_xor(psum, 32);
    l_run = l_run * alpha + psum;
    m_run = mnew;

    // P -> bf16 B-operand frags (kv chunks of 32), pure lane-local
    short8v pb[2];
    #pragma unroll
    for (int c2 = 0; c2 < 2; ++c2) {
      #pragma unroll
      for (int e = 0; e < 4; ++e) {
        pb[c2][e]     = (short)f2bf(st[2 * c2][e]);
        pb[c2][e + 4] = (short)f2bf(st[2 * c2 + 1][e]);
      }
    }

    #pragma unroll
    for (int df = 0; df < 16; ++df) ot[df] *= alpha;

    // PV: O^T += V^T . P^T ; V^T frags via hardware transpose read
    #pragma unroll
    for (int df = 0; df < 16; ++df) {
      short4v v0, v1, v2, v3;
      unsigned ab = vbase + df * 2048;
      asm volatile("ds_read_b64_tr_b16 %0, %1" : "=v"(v0) : "v"(ab));
      asm volatile("ds_read_b64_tr_b16 %0, %1" : "=v"(v1) : "v"(ab + 512));
      asm volatile("ds_read_b64_tr_b16 %0, %1" : "=v"(v2) : "v"(ab + 1024));
      asm volatile("ds_read_b64_tr_b16 %0, %1" : "=v"(v3) : "v"(ab + 1536));
      asm volatile("s_waitcnt lgkmcnt(0)" ::: "memory");
      __builtin_amdgcn_sched_barrier(0);   // rule #18: keep MFMAs below the wait
      ot[df] = __builtin_amdgcn_mfma_f32_16x16x32_bf16(pack8(v0, v1), pb[0], ot[df], 0, 0, 0);
      ot[df] = __builtin_amdgcn_mfma_f32_16x16x32_bf16(pack8(v2, v3), pb[1], ot[df], 0, 0, 0);
    }
    __syncthreads();
  }

  // epilogue: normalize, write attn [B, N, H*DH] bf16
  float inv = 1.0f / l_run;
  const int qrow = q0 + l15;
  const int bb = bh >> 2, h = bh & 3;
  size_t base = ((size_t)(bb * N_ + qrow) * H_ + h) * DH;
  #pragma unroll
  for (int df = 0; df < 16; ++df) {
    ushort4v o;
    #pragma unroll
    for (int e = 0; e < 4; ++e) o[e] = f2bf(ot[df][e] * inv);
    *(ushort4v*)&attn[base + df * 16 + l4 * 4] = o;
  }
}

// ---------------------------------------------------------------------------
// Kernel 3: out = attn[16384,1024](bf16) @ Wo[1024,256](fp32) + bo -> fp32
// ---------------------------------------------------------------------------
__global__ __launch_bounds__(256) void out_gemm(
    const unsigned short* __restrict__ A,
    const float* __restrict__ Wo, const float* __restrict__ bo,
    float* __restrict__ out)
{
  __shared__ __align__(16) unsigned short At[128][40];
  __shared__ __align__(16) unsigned short Bt[128][40];
  const int tid = threadIdx.x;
  const int lane = tid & 63, wid = tid >> 6;
  const int l15 = lane & 15, l4 = lane >> 4;
  const int m0 = blockIdx.x * 128;
  const int n0 = blockIdx.y * 128;
  const int wm = (wid >> 1) * 64, wn = (wid & 1) * 64;
  f32x4 acc[4][4] = {};

  for (int kt = 0; kt < 1024; kt += 32) {
    #pragma unroll
    for (int c = 0; c < 2; ++c) {
      int idx = c * 256 + tid;
      int r = idx >> 2, k8 = (idx & 3) * 8;
      *(ushort8v*)&At[r][k8] = *(const ushort8v*)(A + (size_t)(m0 + r) * 1024 + kt + k8);
    }
    #pragma unroll
    for (int c = 0; c < 4; ++c) {
      int idx = c * 256 + tid;
      int kr = idx >> 5, n4 = (idx & 31) << 2;
      float4v wv = *(const float4v*)(Wo + (size_t)(kt + kr) * 256 + n0 + n4);
      Bt[n4 + 0][kr] = f2bf(wv[0]);
      Bt[n4 + 1][kr] = f2bf(wv[1]);
      Bt[n4 + 2][kr] = f2bf(wv[2]);
      Bt[n4 + 3][kr] = f2bf(wv[3]);
    }
    __syncthreads();

    short8v a[4], b[4];
    #pragma unroll
    for (int mf = 0; mf < 4; ++mf) {
      int r = wm + mf * 16 + l15, kk = l4 * 4;
      short4v lo = *(const short4v*)&At[r][kk];
      short4v hi = *(const short4v*)&At[r][kk + 16];
      a[mf] = pack8(lo, hi);
    }
    #pragma unroll
    for (int nf = 0; nf < 4; ++nf) {
      int r = wn + nf * 16 + l15, kk = l4 * 4;
      short4v lo = *(const short4v*)&Bt[r][kk];
      short4v hi = *(const short4v*)&Bt[r][kk + 16];
      b[nf] = pack8(lo, hi);
    }
    #pragma unroll
    for (int mf = 0; mf < 4; ++mf)
      #pragma unroll
      for (int nf = 0; nf < 4; ++nf)
        acc[mf][nf] = __builtin_amdgcn_mfma_f32_16x16x32_bf16(a[mf], b[nf], acc[mf][nf], 0, 0, 0);
    __syncthreads();
  }

  #pragma unroll
  for (int nf = 0; nf < 4; ++nf) {
    int ncol = n0 + wn + nf * 16 + l15;
    float bv_ = bo[ncol];
    #pragma unroll
    for (int mf = 0; mf < 4; ++mf)
      #pragma unroll
      for (int e = 0; e < 4; ++e) {
        int mrow = m0 + wm + mf * 16 + l4 * 4 + e;
        out[(size_t)mrow * 256 + ncol] = acc[mf][nf][e] + bv_;
      }
  }
}

// ---------------------------------------------------------------------------
extern "C" void kernel_launch(void* const* d_in, const int* in_sizes, int n_in,
                              void* d_out, int out_size, void* d_ws, size_t ws_size,
                              hipStream_t stream) {
  const float* x  = (const float*)d_in[0];
  const float* Wq = (const float*)d_in[1];
  const float* bq = (const float*)d_in[2];
  const float* Wk = (const float*)d_in[3];
  const float* bk = (const float*)d_in[4];
  const float* Wv = (const float*)d_in[5];
  const float* bv = (const float*)d_in[6];
  const float* Wo = (const float*)d_in[7];
  const float* bo = (const float*)d_in[8];

  unsigned short* ws   = (unsigned short*)d_ws;       // Q | K | V | attn (bf16)
  unsigned short* attn = ws + (size_t)3 * QSZ;        // total 4*QSZ*2 = 128 MB
  float* out = (float*)d_out;

  qkv_gemm <<<dim3(128, 24), 256, 0, stream>>>(x, Wq, bq, Wk, bk, Wv, bv, ws);
  attn_fused<<<dim3(32, 32),  256, 0, stream>>>(ws, attn);
  out_gemm <<<dim3(128, 2),  256, 0, stream>>>(attn, Wo, bo, out);
}

// Round 2
// 860.672 us; speedup vs baseline: 1.7509x; 1.7509x over previous
//
#include <hip/hip_runtime.h>
#include <hip/hip_bf16.h>
#include <stdint.h>

typedef __attribute__((ext_vector_type(4))) float  f32x4;
typedef __attribute__((ext_vector_type(4))) float  float4v;
typedef __attribute__((ext_vector_type(8))) short  short8v;
typedef __attribute__((ext_vector_type(4))) short  short4v;
typedef __attribute__((ext_vector_type(8))) unsigned short ushort8v;
typedef __attribute__((ext_vector_type(4))) unsigned short ushort4v;

#define B_   8
#define N_   2048
#define DIN  1024
#define H_   4
#define DH   256
#define QSZ  (B_ * H_ * N_ * DH)   // 16,777,216 elements per tensor

__device__ __forceinline__ unsigned short f2bf(float x) {
  union { float f; unsigned u; } v; v.f = x;
  unsigned r = v.u + 0x7fffu + ((v.u >> 16) & 1u);   // RNE
  return (unsigned short)(r >> 16);
}

__device__ __forceinline__ short8v pack8(short4v lo, short4v hi) {
  short8v r;
  r[0] = lo[0]; r[1] = lo[1]; r[2] = lo[2]; r[3] = lo[3];
  r[4] = hi[0]; r[5] = hi[1]; r[6] = hi[2]; r[7] = hi[3];
  return r;
}

__device__ __forceinline__ void gload_lds16(const void* g, void* l) {
  __builtin_amdgcn_global_load_lds(
      (const __attribute__((address_space(1))) unsigned int*)g,
      (__attribute__((address_space(3))) unsigned int*)l, 16, 0, 0);
}

// ---------------------------------------------------------------------------
// Kernel 1: QKV projection (unchanged this round).
// ---------------------------------------------------------------------------
__global__ __launch_bounds__(256) void qkv_gemm(
    const float* __restrict__ x,
    const float* __restrict__ Wq, const float* __restrict__ bq,
    const float* __restrict__ Wk, const float* __restrict__ bk,
    const float* __restrict__ Wv, const float* __restrict__ bv,
    unsigned short* __restrict__ qkv)
{
  __shared__ __align__(16) unsigned short At[128][40];
  __shared__ __align__(16) unsigned short Bt[128][40];
  const int tid = threadIdx.x;
  const int lane = tid & 63, wid = tid >> 6;
  const int l15 = lane & 15, l4 = lane >> 4;
  const int m0 = blockIdx.x * 128;
  const int bc = blockIdx.y;
  const int wsel = bc >> 3;
  const int c0 = (bc & 7) * 128;
  const float* W    = (wsel == 0) ? Wq : (wsel == 1) ? Wk : Wv;
  const float* bias = (wsel == 0) ? bq : (wsel == 1) ? bk : bv;
  const int wm = (wid >> 1) * 64, wn = (wid & 1) * 64;

  f32x4 acc[4][4] = {};

  for (int kt = 0; kt < DIN; kt += 32) {
    #pragma unroll
    for (int c = 0; c < 4; ++c) {
      int idx = c * 256 + tid;
      int r = idx >> 3, k4 = (idx & 7) << 2;
      float4v xv = *(const float4v*)(x + (size_t)(m0 + r) * DIN + kt + k4);
      ushort4v h;
      h[0] = f2bf(xv[0]); h[1] = f2bf(xv[1]); h[2] = f2bf(xv[2]); h[3] = f2bf(xv[3]);
      *(ushort4v*)&At[r][k4] = h;
    }
    #pragma unroll
    for (int c = 0; c < 4; ++c) {
      int idx = c * 256 + tid;
      int kr = idx >> 5, n4 = (idx & 31) << 2;
      float4v wv = *(const float4v*)(W + (size_t)(kt + kr) * 1024 + c0 + n4);
      Bt[n4 + 0][kr] = f2bf(wv[0]);
      Bt[n4 + 1][kr] = f2bf(wv[1]);
      Bt[n4 + 2][kr] = f2bf(wv[2]);
      Bt[n4 + 3][kr] = f2bf(wv[3]);
    }
    __syncthreads();

    short8v a[4], b[4];
    #pragma unroll
    for (int mf = 0; mf < 4; ++mf) {
      int r = wm + mf * 16 + l15, kk = l4 * 4;
      a[mf] = pack8(*(const short4v*)&At[r][kk], *(const short4v*)&At[r][kk + 16]);
    }
    #pragma unroll
    for (int nf = 0; nf < 4; ++nf) {
      int r = wn + nf * 16 + l15, kk = l4 * 4;
      b[nf] = pack8(*(const short4v*)&Bt[r][kk], *(const short4v*)&Bt[r][kk + 16]);
    }
    #pragma unroll
    for (int mf = 0; mf < 4; ++mf)
      #pragma unroll
      for (int nf = 0; nf < 4; ++nf)
        acc[mf][nf] = __builtin_amdgcn_mfma_f32_16x16x32_bf16(a[mf], b[nf], acc[mf][nf], 0, 0, 0);
    __syncthreads();
  }

  const float scale = (wsel == 0) ? 0.0625f : 1.0f;
  unsigned short* dst = qkv + (size_t)wsel * QSZ;
  #pragma unroll
  for (int nf = 0; nf < 4; ++nf) {
    int ncol = c0 + wn + nf * 16 + l15;
    float bv_ = bias[ncol];
    int h = ncol >> 8, d = ncol & 255;
    #pragma unroll
    for (int mf = 0; mf < 4; ++mf) {
      #pragma unroll
      for (int e = 0; e < 4; ++e) {
        int mrow = m0 + wm + mf * 16 + l4 * 4 + e;
        int bb = mrow >> 11, n = mrow & 2047;
        float val = (acc[mf][nf][e] + bv_) * scale;
        dst[((size_t)(bb * H_ + h) * N_ + n) * DH + d] = f2bf(val);
      }
    }
  }
}

// ---------------------------------------------------------------------------
// Kernel 2: flash attention, swapped-operand 16x16 MFMA, 32 q-rows/wave.
// KVBLK=32, double-buffered LDS staged via global_load_lds (width 16).
// Layout per buffer: K then V, each [dblk=16][kv=32][dcol=16] bf16 subtiles.
// ---------------------------------------------------------------------------
__global__ __launch_bounds__(256) void attn_fused(
    const unsigned short* __restrict__ qkv,
    unsigned short* __restrict__ attn)
{
  __shared__ __align__(16) unsigned short lds[2][16384];   // 2 x 32 KB
  const int tid = threadIdx.x;
  const int lane = tid & 63, wid = tid >> 6;
  const int l15 = lane & 15, l4 = lane >> 4;

  // bijective XCD swizzle: 4 consecutive bh per XCD chunk
  const int id0 = blockIdx.x;                 // 0..511
  const int swz = (id0 & 7) * 64 + (id0 >> 3);
  const int qt = swz & 15, bh = swz >> 4;

  const unsigned short* Qh = qkv + (size_t)bh * N_ * DH;
  const unsigned short* Kh = qkv + (size_t)QSZ + (size_t)bh * N_ * DH;
  const unsigned short* Vh = qkv + (size_t)2 * QSZ + (size_t)bh * N_ * DH;

  // Q fragments: 2 q-groups x 8 k-steps (32 q-rows per wave)
  const int q0 = qt * 128 + wid * 32;
  short8v qf0[8], qf1[8];
  #pragma unroll
  for (int ks = 0; ks < 8; ++ks) {
    const unsigned short* p0 = Qh + (size_t)(q0 + l15) * DH + ks * 32 + l4 * 4;
    const unsigned short* p1 = Qh + (size_t)(q0 + 16 + l15) * DH + ks * 32 + l4 * 4;
    qf0[ks] = pack8(*(const short4v*)p0, *(const short4v*)(p0 + 16));
    qf1[ks] = pack8(*(const short4v*)p1, *(const short4v*)(p1 + 16));
  }

  // staging: chunk i = r*256 + wid*64 + lane -> global byte offset (same for K,V)
  int goff[4];
  #pragma unroll
  for (int r = 0; r < 4; ++r) {
    int i = r * 256 + wid * 64 + lane;
    goff[r] = ((i >> 1) & 31) * 512 + (i >> 6) * 32 + (i & 1) * 16;
  }

  #define STAGE(t, b)                                                        \
    {                                                                        \
      const char* Kg = (const char*)Kh + (size_t)(t) * 16384;                \
      const char* Vg = (const char*)Vh + (size_t)(t) * 16384;                \
      _Pragma("unroll")                                                      \
      for (int r = 0; r < 4; ++r) {                                          \
        gload_lds16(Kg + goff[r], &lds[b][r * 2048 + wid * 512]);            \
        gload_lds16(Vg + goff[r], &lds[b][8192 + r * 2048 + wid * 512]);     \
      }                                                                      \
    }

  f32x4 ot0[16] = {}, ot1[16] = {};
  float m0r = -1.0e30f, m1r = -1.0e30f, l0r = 0.0f, l1r = 0.0f;

  STAGE(0, 0);
  __syncthreads();

  for (int t = 0; t < N_ / 32; ++t) {
    const int cur = t & 1;
    if (t + 1 < N_ / 32) STAGE(t + 1, cur ^ 1);

    const unsigned short* Kb = &lds[cur][0];
    // ---- QK^T (S^T = K . Q^T): st[kf][qi], kv = kf*16 + l4*4+e, q = l15 ----
    f32x4 st00 = {0,0,0,0}, st01 = {0,0,0,0}, st10 = {0,0,0,0}, st11 = {0,0,0,0};
    #pragma unroll
    for (int ks = 0; ks < 8; ++ks) {
      const unsigned short* a0 = &Kb[ks * 1024 + l15 * 16 + l4 * 4];
      const unsigned short* a1 = &Kb[ks * 1024 + (16 + l15) * 16 + l4 * 4];
      short8v af0 = pack8(*(const short4v*)a0, *(const short4v*)(a0 + 512));
      short8v af1 = pack8(*(const short4v*)a1, *(const short4v*)(a1 + 512));
      st00 = __builtin_amdgcn_mfma_f32_16x16x32_bf16(af0, qf0[ks], st00, 0, 0, 0);
      st01 = __builtin_amdgcn_mfma_f32_16x16x32_bf16(af0, qf1[ks], st01, 0, 0, 0);
      st10 = __builtin_amdgcn_mfma_f32_16x16x32_bf16(af1, qf0[ks], st10, 0, 0, 0);
      st11 = __builtin_amdgcn_mfma_f32_16x16x32_bf16(af1, qf1[ks], st11, 0, 0, 0);
    }

    // ---- online softmax with defer-max (THR = 8) ----
    short8v pb0, pb1;
    {
      float tmax = fmaxf(fmaxf(st00[0], st00[1]), fmaxf(st00[2], st00[3]));
      tmax = fmaxf(tmax, fmaxf(fmaxf(st10[0], st10[1]), fmaxf(st10[2], st10[3])));
      tmax = fmaxf(tmax, __shfl_xor(tmax, 16));
      tmax = fmaxf(tmax, __shfl_xor(tmax, 32));
      if (__any(tmax > m0r + 8.0f)) {
        float mn = fmaxf(m0r, tmax), al = __expf(m0r - mn);
        l0r *= al;
        #pragma unroll
        for (int df = 0; df < 16; ++df) ot0[df] *= al;
        m0r = mn;
      }
      float psum = 0.0f;
      #pragma unroll
      for (int e = 0; e < 4; ++e) {
        float p0 = __expf(st00[e] - m0r), p1 = __expf(st10[e] - m0r);
        pb0[e] = (short)f2bf(p0); pb0[e + 4] = (short)f2bf(p1);
        psum += p0 + p1;
      }
      psum += __shfl_xor(psum, 16);
      psum += __shfl_xor(psum, 32);
      l0r += psum;
    }
    {
      float tmax = fmaxf(fmaxf(st01[0], st01[1]), fmaxf(st01[2], st01[3]));
      tmax = fmaxf(tmax, fmaxf(fmaxf(st11[0], st11[1]), fmaxf(st11[2], st11[3])));
      tmax = fmaxf(tmax, __shfl_xor(tmax, 16));
      tmax = fmaxf(tmax, __shfl_xor(tmax, 32));
      if (__any(tmax > m1r + 8.0f)) {
        float mn = fmaxf(m1r, tmax), al = __expf(m1r - mn);
        l1r *= al;
        #pragma unroll
        for (int df = 0; df < 16; ++df) ot1[df] *= al;
        m1r = mn;
      }
      float psum = 0.0f;
      #pragma unroll
      for (int e = 0; e < 4; ++e) {
        float p0 = __expf(st01[e] - m1r), p1 = __expf(st11[e] - m1r);
        pb1[e] = (short)f2bf(p0); pb1[e + 4] = (short)f2bf(p1);
        psum += p0 + p1;
      }
      psum += __shfl_xor(psum, 16);
      psum += __shfl_xor(psum, 32);
      l1r += psum;
    }

    // ---- PV: O^T += V^T . P^T, pipelined tr_reads (counted lgkmcnt) ----
    const unsigned vb = (unsigned)(uintptr_t)(&lds[cur][8192]) + lane * 8;
    asm volatile("s_waitcnt lgkmcnt(0)" ::: "memory");
    __builtin_amdgcn_sched_barrier(0);
    short4v va0, va1, vn0, vn1;
    asm volatile("ds_read_b64_tr_b16 %0, %1" : "=v"(va0) : "v"(vb));
    asm volatile("ds_read_b64_tr_b16 %0, %1" : "=v"(va1) : "v"(vb + 512));
    #pragma unroll
    for (int df = 0; df < 16; ++df) {
      if (df < 15) {
        unsigned nb = vb + (unsigned)(df + 1) * 1024;
        asm volatile("ds_read_b64_tr_b16 %0, %1" : "=v"(vn0) : "v"(nb));
        asm volatile("ds_read_b64_tr_b16 %0, %1" : "=v"(vn1) : "v"(nb + 512));
        asm volatile("s_waitcnt lgkmcnt(2)" ::: "memory");
      } else {
        asm volatile("s_waitcnt lgkmcnt(0)" ::: "memory");
      }
      __builtin_amdgcn_sched_barrier(0);
      short8v vf = pack8(va0, va1);
      ot0[df] = __builtin_amdgcn_mfma_f32_16x16x32_bf16(vf, pb0, ot0[df], 0, 0, 0);
      ot1[df] = __builtin_amdgcn_mfma_f32_16x16x32_bf16(vf, pb1, ot1[df], 0, 0, 0);
      va0 = vn0; va1 = vn1;
    }

    __syncthreads();   // drains vmcnt(0) lgkmcnt(0): next tile staged, all reads done
  }

  // ---- epilogue: normalize, write attn [B, N, H*DH] bf16 ----
  const int bb = bh >> 2, h = bh & 3;
  {
    float inv = 1.0f / l0r;
    size_t base = ((size_t)(bb * N_ + q0 + l15)) * (H_ * DH) + h * DH;
    #pragma unroll
    for (int df = 0; df < 16; ++df) {
      ushort4v o;
      #pragma unroll
      for (int e = 0; e < 4; ++e) o[e] = f2bf(ot0[df][e] * inv);
      *(ushort4v*)&attn[base + df * 16 + l4 * 4] = o;
    }
  }
  {
    float inv = 1.0f / l1r;
    size_t base = ((size_t)(bb * N_ + q0 + 16 + l15)) * (H_ * DH) + h * DH;
    #pragma unroll
    for (int df = 0; df < 16; ++df) {
      ushort4v o;
      #pragma unroll
      for (int e = 0; e < 4; ++e) o[e] = f2bf(ot1[df][e] * inv);
      *(ushort4v*)&attn[base + df * 16 + l4 * 4] = o;
    }
  }
  #undef STAGE
}

// ---------------------------------------------------------------------------
// Kernel 3: out = attn[16384,1024](bf16) @ Wo[1024,256](fp32) + bo -> fp32
// ---------------------------------------------------------------------------
__global__ __launch_bounds__(256) void out_gemm(
    const unsigned short* __restrict__ A,
    const float* __restrict__ Wo, const float* __restrict__ bo,
    float* __restrict__ out)
{
  __shared__ __align__(16) unsigned short At[128][40];
  __shared__ __align__(16) unsigned short Bt[128][40];
  const int tid = threadIdx.x;
  const int lane = tid & 63, wid = tid >> 6;
  const int l15 = lane & 15, l4 = lane >> 4;
  const int m0 = blockIdx.x * 128;
  const int n0 = blockIdx.y * 128;
  const int wm = (wid >> 1) * 64, wn = (wid & 1) * 64;
  f32x4 acc[4][4] = {};

  for (int kt = 0; kt < 1024; kt += 32) {
    #pragma unroll
    for (int c = 0; c < 2; ++c) {
      int idx = c * 256 + tid;
      int r = idx >> 2, k8 = (idx & 3) * 8;
      *(ushort8v*)&At[r][k8] = *(const ushort8v*)(A + (size_t)(m0 + r) * 1024 + kt + k8);
    }
    #pragma unroll
    for (int c = 0; c < 4; ++c) {
      int idx = c * 256 + tid;
      int kr = idx >> 5, n4 = (idx & 31) << 2;
      float4v wv = *(const float4v*)(Wo + (size_t)(kt + kr) * 256 + n0 + n4);
      Bt[n4 + 0][kr] = f2bf(wv[0]);
      Bt[n4 + 1][kr] = f2bf(wv[1]);
      Bt[n4 + 2][kr] = f2bf(wv[2]);
      Bt[n4 + 3][kr] = f2bf(wv[3]);
    }
    __syncthreads();

    short8v a[4], b[4];
    #pragma unroll
    for (int mf = 0; mf < 4; ++mf) {
      int r = wm + mf * 16 + l15, kk = l4 * 4;
      a[mf] = pack8(*(const short4v*)&At[r][kk], *(const short4v*)&At[r][kk + 16]);
    }
    #pragma unroll
    for (int nf = 0; nf < 4; ++nf) {
      int r = wn + nf * 16 + l15, kk = l4 * 4;
      b[nf] = pack8(*(const short4v*)&Bt[r][kk], *(const short4v*)&Bt[r][kk + 16]);
    }
    #pragma unroll
    for (int mf = 0; mf < 4; ++mf)
      #pragma unroll
      for (int nf = 0; nf < 4; ++nf)
        acc[mf][nf] = __builtin_amdgcn_mfma_f32_16x16x32_bf16(a[mf], b[nf], acc[mf][nf], 0, 0, 0);
    __syncthreads();
  }

  #pragma unroll
  for (int nf = 0; nf < 4; ++nf) {
    int ncol = n0 + wn + nf * 16 + l15;
    float bv_ = bo[ncol];
    #pragma unroll
    for (int mf = 0; mf < 4; ++mf)
      #pragma unroll
      for (int e = 0; e < 4; ++e) {
        int mrow = m0 + wm + mf * 16 + l4 * 4 + e;
        out[(size_t)mrow * 256 + ncol] = acc[mf][nf][e] + bv_;
      }
  }
}

// ---------------------------------------------------------------------------
extern "C" void kernel_launch(void* const* d_in, const int* in_sizes, int n_in,
                              void* d_out, int out_size, void* d_ws, size_t ws_size,
                              hipStream_t stream) {
  const float* x  = (const float*)d_in[0];
  const float* Wq = (const float*)d_in[1];
  const float* bq = (const float*)d_in[2];
  const float* Wk = (const float*)d_in[3];
  const float* bk = (const float*)d_in[4];
  const float* Wv = (const float*)d_in[5];
  const float* bv = (const float*)d_in[6];
  const float* Wo = (const float*)d_in[7];
  const float* bo = (const float*)d_in[8];

  unsigned short* ws   = (unsigned short*)d_ws;
  unsigned short* attn = ws + (size_t)3 * QSZ;
  float* out = (float*)d_out;

  qkv_gemm <<<dim3(128, 24), 256, 0, stream>>>(x, Wq, bq, Wk, bk, Wv, bv, ws);
  attn_fused<<<dim3(512), 256, 0, stream>>>(ws, attn);
  out_gemm <<<dim3(128, 2), 256, 0, stream>>>(attn, Wo, bo, out);
}

// Round 3
// 424.491 us; speedup vs baseline: 3.5500x; 2.0275x over previous
//
#include <hip/hip_runtime.h>
#include <hip/hip_bf16.h>
#include <stdint.h>

typedef __attribute__((ext_vector_type(4))) float  f32x4;
typedef __attribute__((ext_vector_type(4))) float  float4v;
typedef __attribute__((ext_vector_type(8))) short  short8v;
typedef __attribute__((ext_vector_type(4))) short  short4v;
typedef __attribute__((ext_vector_type(8))) unsigned short ushort8v;
typedef __attribute__((ext_vector_type(4))) unsigned short ushort4v;

#define B_   8
#define N_   2048
#define DIN  1024
#define H_   4
#define DH   256
#define QSZ  (B_ * H_ * N_ * DH)   // 16,777,216 elements per tensor

__device__ __forceinline__ unsigned short f2bf(float x) {
  union { float f; unsigned u; } v; v.f = x;
  unsigned r = v.u + 0x7fffu + ((v.u >> 16) & 1u);   // RNE
  return (unsigned short)(r >> 16);
}

__device__ __forceinline__ short8v pack8(short4v lo, short4v hi) {
  short8v r;
  r[0] = lo[0]; r[1] = lo[1]; r[2] = lo[2]; r[3] = lo[3];
  r[4] = hi[0]; r[5] = hi[1]; r[6] = hi[2]; r[7] = hi[3];
  return r;
}

__device__ __forceinline__ void gload_lds16(const void* g, void* l) {
  __builtin_amdgcn_global_load_lds(
      (const __attribute__((address_space(1))) unsigned int*)g,
      (__attribute__((address_space(3))) unsigned int*)l, 16, 0, 0);
}

// ---------------------------------------------------------------------------
// Prep: Wt[c][k] = bf16(W[k][c]) for c in [0,3328): Wq|Wk|Wv cols 0..3071,
// Wo cols 3072..3327.  64x64 fp32 LDS tile transpose.
// ---------------------------------------------------------------------------
__global__ __launch_bounds__(256) void prep_wt(
    const float* __restrict__ Wq, const float* __restrict__ Wk,
    const float* __restrict__ Wv, const float* __restrict__ Wo,
    unsigned short* __restrict__ Wt)
{
  __shared__ float Lt[64][68];
  const int tid = threadIdx.x;
  const int c0 = blockIdx.x * 64;     // 0..3327
  const int k0 = blockIdx.y * 64;
  const int msel = c0 >> 10;
  const float* src = (msel == 0) ? Wq : (msel == 1) ? Wk : (msel == 2) ? Wv : Wo;
  const int stride = (msel == 3) ? 256 : 1024;
  const int cloc = c0 - msel * 1024;
  #pragma unroll
  for (int p = 0; p < 4; ++p) {
    int kr = p * 16 + (tid >> 4), c4 = (tid & 15) * 4;
    float4v v = *(const float4v*)(src + (size_t)(k0 + kr) * stride + cloc + c4);
    Lt[kr][c4 + 0] = v[0]; Lt[kr][c4 + 1] = v[1];
    Lt[kr][c4 + 2] = v[2]; Lt[kr][c4 + 3] = v[3];
  }
  __syncthreads();
  int n = tid >> 2, kc = (tid & 3) * 16;
  ushort8v h0, h1;
  #pragma unroll
  for (int j = 0; j < 8; ++j) h0[j] = f2bf(Lt[kc + j][n]);
  #pragma unroll
  for (int j = 0; j < 8; ++j) h1[j] = f2bf(Lt[kc + 8 + j][n]);
  unsigned short* dst = Wt + (size_t)(c0 + n) * 1024 + k0 + kc;
  *(ushort8v*)dst = h0;
  *(ushort8v*)(dst + 8) = h1;
}

// ---------------------------------------------------------------------------
// Kernel 1: QKV GEMM, 128m x 256n tile, BK=32, 8 waves (2m x 4n), dbuf LDS.
// B staged via global_load_lds from bf16 Wt; A reg-staged fp32->bf16.
// Output bf16 [B,H,N,DH]; Q scaled by 1/16.
// ---------------------------------------------------------------------------
__global__ __launch_bounds__(512) void qkv_gemm2(
    const float* __restrict__ x, const unsigned short* __restrict__ Wt,
    const float* __restrict__ bq, const float* __restrict__ bk,
    const float* __restrict__ bv, unsigned short* __restrict__ qkv)
{
  __shared__ __align__(16) unsigned short Ab[2][4096];   // [128][32] bf16
  __shared__ __align__(16) unsigned short Bb[2][8192];   // [256][32] bf16
  const int tid = threadIdx.x;
  const int lane = tid & 63, wid = tid >> 6;
  const int l15 = lane & 15, l4 = lane >> 4;

  // XCD swizzle (1536 = 8*192, bijective); bx-major so 12 consecutive works
  // on one XCD share the same 512KB x-panel via L2.
  const int id = blockIdx.x;
  const int swz = (id & 7) * 192 + (id >> 3);
  const int m0 = (swz / 12) * 128, n0 = (swz % 12) * 256;
  const int wm = (wid >> 2) * 64, wn = (wid & 3) * 64;

  const int arow = tid >> 2, akb = (tid & 3) * 16;          // A: 16B LDS per thread
  const int brow1 = wid * 16 + (lane >> 2), bkb = (lane & 3) * 16;
  const float* Abase = x + (size_t)(m0 + arow) * 1024 + (akb >> 1);
  const char* Bg1 = (const char*)Wt + (size_t)(n0 + brow1) * 2048 + bkb;
  const char* Bg2 = Bg1 + 128 * 2048;

  f32x4 acc[4][4] = {};

#define QSTAGE(t, b) do {                                                    \
    float4v f0 = *(const float4v*)(Abase + (t) * 32);                        \
    float4v f1 = *(const float4v*)(Abase + (t) * 32 + 4);                    \
    gload_lds16(Bg1 + (t) * 64, (char*)&Bb[b][0] + wid * 1024);              \
    gload_lds16(Bg2 + (t) * 64, (char*)&Bb[b][0] + 8192 + wid * 1024);       \
    ushort8v hv;                                                             \
    hv[0] = f2bf(f0[0]); hv[1] = f2bf(f0[1]);                                \
    hv[2] = f2bf(f0[2]); hv[3] = f2bf(f0[3]);                                \
    hv[4] = f2bf(f1[0]); hv[5] = f2bf(f1[1]);                                \
    hv[6] = f2bf(f1[2]); hv[7] = f2bf(f1[3]);                                \
    *(ushort8v*)((char*)&Ab[b][0] + tid * 16) = hv;                          \
  } while (0)

  QSTAGE(0, 0);
  __syncthreads();

  for (int t = 0; t < 32; ++t) {
    const int cur = t & 1;
    if (t < 31) QSTAGE(t + 1, cur ^ 1);
    short8v a[4], b[4];
    #pragma unroll
    for (int mf = 0; mf < 4; ++mf)
      a[mf] = *(const short8v*)((const char*)&Ab[cur][0] +
                                (wm + mf * 16 + l15) * 64 + l4 * 16);
    #pragma unroll
    for (int nf = 0; nf < 4; ++nf)
      b[nf] = *(const short8v*)((const char*)&Bb[cur][0] +
                                (wn + nf * 16 + l15) * 64 + l4 * 16);
    #pragma unroll
    for (int mf = 0; mf < 4; ++mf)
      #pragma unroll
      for (int nf = 0; nf < 4; ++nf)
        acc[mf][nf] = __builtin_amdgcn_mfma_f32_16x16x32_bf16(a[mf], b[nf], acc[mf][nf], 0, 0, 0);
    __syncthreads();
  }
#undef QSTAGE

  const int wsel = n0 >> 10;                       // uniform per block
  const float* bias = (wsel == 0) ? bq : (wsel == 1) ? bk : bv;
  const float scale = (wsel == 0) ? 0.0625f : 1.0f;
  unsigned short* dst = qkv + (size_t)wsel * QSZ;
  #pragma unroll
  for (int nf = 0; nf < 4; ++nf) {
    int ncol = n0 + wn + nf * 16 + l15;
    int ncl = ncol & 1023;
    float bv_ = bias[ncl];
    int h = ncl >> 8, d = ncl & 255;
    #pragma unroll
    for (int mf = 0; mf < 4; ++mf)
      #pragma unroll
      for (int e = 0; e < 4; ++e) {
        int mrow = m0 + wm + mf * 16 + l4 * 4 + e;
        int bb = mrow >> 11, nn = mrow & 2047;
        dst[((size_t)(bb * 4 + h) * 2048 + nn) * 256 + d] =
            f2bf((acc[mf][nf][e] + bv_) * scale);
      }
  }
}

// ---------------------------------------------------------------------------
// Kernel 2: flash attention (round-2 structure), output written IN PLACE over
// the block's own Q rows ([B,H,N,DH] layout) to save workspace.
// ---------------------------------------------------------------------------
__global__ __launch_bounds__(256) void attn_fused(
    unsigned short* __restrict__ qkv)
{
  __shared__ __align__(16) unsigned short lds[2][16384];   // 2 x 32 KB
  const int tid = threadIdx.x;
  const int lane = tid & 63, wid = tid >> 6;
  const int l15 = lane & 15, l4 = lane >> 4;

  const int id0 = blockIdx.x;                 // 0..511
  const int swz = (id0 & 7) * 64 + (id0 >> 3);
  const int qt = swz & 15, bh = swz >> 4;

  const unsigned short* Qh = qkv + (size_t)bh * N_ * DH;
  const unsigned short* Kh = qkv + (size_t)QSZ + (size_t)bh * N_ * DH;
  const unsigned short* Vh = qkv + (size_t)2 * QSZ + (size_t)bh * N_ * DH;

  const int q0 = qt * 128 + wid * 32;
  short8v qf0[8], qf1[8];
  #pragma unroll
  for (int ks = 0; ks < 8; ++ks) {
    const unsigned short* p0 = Qh + (size_t)(q0 + l15) * DH + ks * 32 + l4 * 4;
    const unsigned short* p1 = Qh + (size_t)(q0 + 16 + l15) * DH + ks * 32 + l4 * 4;
    qf0[ks] = pack8(*(const short4v*)p0, *(const short4v*)(p0 + 16));
    qf1[ks] = pack8(*(const short4v*)p1, *(const short4v*)(p1 + 16));
  }

  int goff[4];
  #pragma unroll
  for (int r = 0; r < 4; ++r) {
    int i = r * 256 + wid * 64 + lane;
    goff[r] = ((i >> 1) & 31) * 512 + (i >> 6) * 32 + (i & 1) * 16;
  }

  #define STAGE(t, b)                                                        \
    {                                                                        \
      const char* Kg = (const char*)Kh + (size_t)(t) * 16384;                \
      const char* Vg = (const char*)Vh + (size_t)(t) * 16384;                \
      _Pragma("unroll")                                                      \
      for (int r = 0; r < 4; ++r) {                                          \
        gload_lds16(Kg + goff[r], &lds[b][r * 2048 + wid * 512]);            \
        gload_lds16(Vg + goff[r], &lds[b][8192 + r * 2048 + wid * 512]);     \
      }                                                                      \
    }

  f32x4 ot0[16] = {}, ot1[16] = {};
  float m0r = -1.0e30f, m1r = -1.0e30f, l0r = 0.0f, l1r = 0.0f;

  STAGE(0, 0);
  __syncthreads();

  for (int t = 0; t < N_ / 32; ++t) {
    const int cur = t & 1;
    if (t + 1 < N_ / 32) STAGE(t + 1, cur ^ 1);

    const unsigned short* Kb = &lds[cur][0];
    f32x4 st00 = {0,0,0,0}, st01 = {0,0,0,0}, st10 = {0,0,0,0}, st11 = {0,0,0,0};
    #pragma unroll
    for (int ks = 0; ks < 8; ++ks) {
      const unsigned short* a0 = &Kb[ks * 1024 + l15 * 16 + l4 * 4];
      const unsigned short* a1 = &Kb[ks * 1024 + (16 + l15) * 16 + l4 * 4];
      short8v af0 = pack8(*(const short4v*)a0, *(const short4v*)(a0 + 512));
      short8v af1 = pack8(*(const short4v*)a1, *(const short4v*)(a1 + 512));
      st00 = __builtin_amdgcn_mfma_f32_16x16x32_bf16(af0, qf0[ks], st00, 0, 0, 0);
      st01 = __builtin_amdgcn_mfma_f32_16x16x32_bf16(af0, qf1[ks], st01, 0, 0, 0);
      st10 = __builtin_amdgcn_mfma_f32_16x16x32_bf16(af1, qf0[ks], st10, 0, 0, 0);
      st11 = __builtin_amdgcn_mfma_f32_16x16x32_bf16(af1, qf1[ks], st11, 0, 0, 0);
    }

    short8v pb0, pb1;
    {
      float tmax = fmaxf(fmaxf(st00[0], st00[1]), fmaxf(st00[2], st00[3]));
      tmax = fmaxf(tmax, fmaxf(fmaxf(st10[0], st10[1]), fmaxf(st10[2], st10[3])));
      tmax = fmaxf(tmax, __shfl_xor(tmax, 16));
      tmax = fmaxf(tmax, __shfl_xor(tmax, 32));
      if (__any(tmax > m0r + 8.0f)) {
        float mn = fmaxf(m0r, tmax), al = __expf(m0r - mn);
        l0r *= al;
        #pragma unroll
        for (int df = 0; df < 16; ++df) ot0[df] *= al;
        m0r = mn;
      }
      float psum = 0.0f;
      #pragma unroll
      for (int e = 0; e < 4; ++e) {
        float p0 = __expf(st00[e] - m0r), p1 = __expf(st10[e] - m0r);
        pb0[e] = (short)f2bf(p0); pb0[e + 4] = (short)f2bf(p1);
        psum += p0 + p1;
      }
      psum += __shfl_xor(psum, 16);
      psum += __shfl_xor(psum, 32);
      l0r += psum;
    }
    {
      float tmax = fmaxf(fmaxf(st01[0], st01[1]), fmaxf(st01[2], st01[3]));
      tmax = fmaxf(tmax, fmaxf(fmaxf(st11[0], st11[1]), fmaxf(st11[2], st11[3])));
      tmax = fmaxf(tmax, __shfl_xor(tmax, 16));
      tmax = fmaxf(tmax, __shfl_xor(tmax, 32));
      if (__any(tmax > m1r + 8.0f)) {
        float mn = fmaxf(m1r, tmax), al = __expf(m1r - mn);
        l1r *= al;
        #pragma unroll
        for (int df = 0; df < 16; ++df) ot1[df] *= al;
        m1r = mn;
      }
      float psum = 0.0f;
      #pragma unroll
      for (int e = 0; e < 4; ++e) {
        float p0 = __expf(st01[e] - m1r), p1 = __expf(st11[e] - m1r);
        pb1[e] = (short)f2bf(p0); pb1[e + 4] = (short)f2bf(p1);
        psum += p0 + p1;
      }
      psum += __shfl_xor(psum, 16);
      psum += __shfl_xor(psum, 32);
      l1r += psum;
    }

    const unsigned vb = (unsigned)(uintptr_t)(&lds[cur][8192]) + lane * 8;
    asm volatile("s_waitcnt lgkmcnt(0)" ::: "memory");
    __builtin_amdgcn_sched_barrier(0);
    short4v va0, va1, vn0, vn1;
    asm volatile("ds_read_b64_tr_b16 %0, %1" : "=v"(va0) : "v"(vb));
    asm volatile("ds_read_b64_tr_b16 %0, %1" : "=v"(va1) : "v"(vb + 512));
    #pragma unroll
    for (int df = 0; df < 16; ++df) {
      if (df < 15) {
        unsigned nb = vb + (unsigned)(df + 1) * 1024;
        asm volatile("ds_read_b64_tr_b16 %0, %1" : "=v"(vn0) : "v"(nb));
        asm volatile("ds_read_b64_tr_b16 %0, %1" : "=v"(vn1) : "v"(nb + 512));
        asm volatile("s_waitcnt lgkmcnt(2)" ::: "memory");
      } else {
        asm volatile("s_waitcnt lgkmcnt(0)" ::: "memory");
      }
      __builtin_amdgcn_sched_barrier(0);
      short8v vf = pack8(va0, va1);
      ot0[df] = __builtin_amdgcn_mfma_f32_16x16x32_bf16(vf, pb0, ot0[df], 0, 0, 0);
      ot1[df] = __builtin_amdgcn_mfma_f32_16x16x32_bf16(vf, pb1, ot1[df], 0, 0, 0);
      va0 = vn0; va1 = vn1;
    }

    __syncthreads();
  }

  // epilogue: normalize, overwrite own Q rows (layout [B,H,N,DH])
  unsigned short* Oq = (unsigned short*)Qh;
  {
    float inv = 1.0f / l0r;
    size_t base = (size_t)(q0 + l15) * DH;
    #pragma unroll
    for (int df = 0; df < 16; ++df) {
      ushort4v o;
      #pragma unroll
      for (int e = 0; e < 4; ++e) o[e] = f2bf(ot0[df][e] * inv);
      *(ushort4v*)&Oq[base + df * 16 + l4 * 4] = o;
    }
  }
  {
    float inv = 1.0f / l1r;
    size_t base = (size_t)(q0 + 16 + l15) * DH;
    #pragma unroll
    for (int df = 0; df < 16; ++df) {
      ushort4v o;
      #pragma unroll
      for (int e = 0; e < 4; ++e) o[e] = f2bf(ot1[df][e] * inv);
      *(ushort4v*)&Oq[base + df * 16 + l4 * 4] = o;
    }
  }
  #undef STAGE
}

// ---------------------------------------------------------------------------
// Kernel 3: out[16384][256] = attnO @ Wo + bo.  attnO lives in the Q region,
// layout [B,H,N,DH]; logical row m = bb*2048+q, col k = h*256+d.
// 128m x 256n tile (whole N), 8 waves, BK=32, all-gload staging.
// ---------------------------------------------------------------------------
__global__ __launch_bounds__(512) void out_gemm2(
    const unsigned short* __restrict__ Aq, const unsigned short* __restrict__ WoT,
    const float* __restrict__ bo, float* __restrict__ out)
{
  __shared__ __align__(16) unsigned short Ab[2][4096];
  __shared__ __align__(16) unsigned short Bb[2][8192];
  const int tid = threadIdx.x;
  const int lane = tid & 63, wid = tid >> 6;
  const int l15 = lane & 15, l4 = lane >> 4;
  const int m0 = blockIdx.x * 128;
  const int wm = (wid >> 2) * 64, wn = (wid & 3) * 64;

  const int arow = wid * 16 + (lane >> 2), akb = (lane & 3) * 16;
  const int bb = m0 >> 11;
  const int qrow = (m0 & 2047) + arow;
  const char* Bg1 = (const char*)WoT + (size_t)arow * 2048 + akb;
  const char* Bg2 = Bg1 + 128 * 2048;

  f32x4 acc[4][4] = {};

#define OSTAGE(t, b) do {                                                    \
    int h = (t) >> 3, d0 = (((t) & 7) * 32) + (akb >> 1);                    \
    gload_lds16(Aq + ((size_t)(bb * 4 + h) * 2048 + qrow) * 256 + d0,        \
                (char*)&Ab[b][0] + wid * 1024);                              \
    gload_lds16(Bg1 + (t) * 64, (char*)&Bb[b][0] + wid * 1024);              \
    gload_lds16(Bg2 + (t) * 64, (char*)&Bb[b][0] + 8192 + wid * 1024);       \
  } while (0)

  OSTAGE(0, 0);
  __syncthreads();

  for (int t = 0; t < 32; ++t) {
    const int cur = t & 1;
    if (t < 31) OSTAGE(t + 1, cur ^ 1);
    short8v a[4], b[4];
    #pragma unroll
    for (int mf = 0; mf < 4; ++mf)
      a[mf] = *(const short8v*)((const char*)&Ab[cur][0] +
                                (wm + mf * 16 + l15) * 64 + l4 * 16);
    #pragma unroll
    for (int nf = 0; nf < 4; ++nf)
      b[nf] = *(const short8v*)((const char*)&Bb[cur][0] +
                                (wn + nf * 16 + l15) * 64 + l4 * 16);
    #pragma unroll
    for (int mf = 0; mf < 4; ++mf)
      #pragma unroll
      for (int nf = 0; nf < 4; ++nf)
        acc[mf][nf] = __builtin_amdgcn_mfma_f32_16x16x32_bf16(a[mf], b[nf], acc[mf][nf], 0, 0, 0);
    __syncthreads();
  }
#undef OSTAGE

  #pragma unroll
  for (int nf = 0; nf < 4; ++nf) {
    int ncol = wn + nf * 16 + l15;
    float bv_ = bo[ncol];
    #pragma unroll
    for (int mf = 0; mf < 4; ++mf)
      #pragma unroll
      for (int e = 0; e < 4; ++e) {
        int mrow = m0 + wm + mf * 16 + l4 * 4 + e;
        out[(size_t)mrow * 256 + ncol] = acc[mf][nf][e] + bv_;
      }
  }
}

// ---------------------------------------------------------------------------
extern "C" void kernel_launch(void* const* d_in, const int* in_sizes, int n_in,
                              void* d_out, int out_size, void* d_ws, size_t ws_size,
                              hipStream_t stream) {
  const float* x  = (const float*)d_in[0];
  const float* Wq = (const float*)d_in[1];
  const float* bq = (const float*)d_in[2];
  const float* Wk = (const float*)d_in[3];
  const float* bk = (const float*)d_in[4];
  const float* Wv = (const float*)d_in[5];
  const float* bv = (const float*)d_in[6];
  const float* Wo = (const float*)d_in[7];
  const float* bo = (const float*)d_in[8];

  unsigned short* qkvbuf = (unsigned short*)d_ws;       // Q|K|V bf16 (96 MiB)
  unsigned short* Wt     = qkvbuf + (size_t)3 * QSZ;    // [3328][1024] bf16 (6.5 MiB)
  float* out = (float*)d_out;

  prep_wt  <<<dim3(52, 16), 256, 0, stream>>>(Wq, Wk, Wv, Wo, Wt);
  qkv_gemm2<<<dim3(1536),   512, 0, stream>>>(x, Wt, bq, bk, bv, qkvbuf);
  attn_fused<<<dim3(512),   256, 0, stream>>>(qkvbuf);
  out_gemm2<<<dim3(128),    512, 0, stream>>>(qkvbuf, Wt + (size_t)3072 * 1024, bo, out);
}

// Round 4
// 400.332 us; speedup vs baseline: 3.7642x; 1.0603x over previous
//
#include <hip/hip_runtime.h>
#include <hip/hip_bf16.h>
#include <stdint.h>

typedef __attribute__((ext_vector_type(4))) float  f32x4;
typedef __attribute__((ext_vector_type(4))) float  float4v;
typedef __attribute__((ext_vector_type(8))) short  short8v;
typedef __attribute__((ext_vector_type(4))) short  short4v;
typedef __attribute__((ext_vector_type(8))) unsigned short ushort8v;
typedef __attribute__((ext_vector_type(4))) unsigned short ushort4v;

#define B_   8
#define N_   2048
#define DIN  1024
#define H_   4
#define DH   256
#define QSZ  (B_ * N_ * H_ * DH)   // 16,777,216 elements per tensor

__device__ __forceinline__ unsigned short f2bf(float x) {
  union { float f; unsigned u; } v; v.f = x;
  unsigned r = v.u + 0x7fffu + ((v.u >> 16) & 1u);   // RNE
  return (unsigned short)(r >> 16);
}

__device__ __forceinline__ short8v pack8(short4v lo, short4v hi) {
  short8v r;
  r[0] = lo[0]; r[1] = lo[1]; r[2] = lo[2]; r[3] = lo[3];
  r[4] = hi[0]; r[5] = hi[1]; r[6] = hi[2]; r[7] = hi[3];
  return r;
}

__device__ __forceinline__ ushort4v ulo4(ushort8v v) {
  ushort4v r; r[0] = v[0]; r[1] = v[1]; r[2] = v[2]; r[3] = v[3]; return r;
}
__device__ __forceinline__ ushort4v uhi4(ushort8v v) {
  ushort4v r; r[0] = v[4]; r[1] = v[5]; r[2] = v[6]; r[3] = v[7]; return r;
}
__device__ __forceinline__ ushort8v umk8(ushort4v a, ushort4v b) {
  ushort8v r;
  r[0] = a[0]; r[1] = a[1]; r[2] = a[2]; r[3] = a[3];
  r[4] = b[0]; r[5] = b[1]; r[6] = b[2]; r[7] = b[3];
  return r;
}

__device__ __forceinline__ void gload_lds16(const void* g, void* l) {
  __builtin_amdgcn_global_load_lds(
      (const __attribute__((address_space(1))) unsigned int*)g,
      (__attribute__((address_space(3))) unsigned int*)l, 16, 0, 0);
}

// ---------------------------------------------------------------------------
// Prep: Wt[c][k] = bf16(W[k][c]) for c in [0,3328): Wq|Wk|Wv cols 0..3071,
// Wo cols 3072..3327.  64x64 fp32 LDS tile transpose.
// ---------------------------------------------------------------------------
__global__ __launch_bounds__(256) void prep_wt(
    const float* __restrict__ Wq, const float* __restrict__ Wk,
    const float* __restrict__ Wv, const float* __restrict__ Wo,
    unsigned short* __restrict__ Wt)
{
  __shared__ float Lt[64][68];
  const int tid = threadIdx.x;
  const int c0 = blockIdx.x * 64;     // 0..3327
  const int k0 = blockIdx.y * 64;
  const int msel = c0 >> 10;
  const float* src = (msel == 0) ? Wq : (msel == 1) ? Wk : (msel == 2) ? Wv : Wo;
  const int stride = (msel == 3) ? 256 : 1024;
  const int cloc = c0 - msel * 1024;
  #pragma unroll
  for (int p = 0; p < 4; ++p) {
    int kr = p * 16 + (tid >> 4), c4 = (tid & 15) * 4;
    float4v v = *(const float4v*)(src + (size_t)(k0 + kr) * stride + cloc + c4);
    Lt[kr][c4 + 0] = v[0]; Lt[kr][c4 + 1] = v[1];
    Lt[kr][c4 + 2] = v[2]; Lt[kr][c4 + 3] = v[3];
  }
  __syncthreads();
  int n = tid >> 2, kc = (tid & 3) * 16;
  ushort8v h0, h1;
  #pragma unroll
  for (int j = 0; j < 8; ++j) h0[j] = f2bf(Lt[kc + j][n]);
  #pragma unroll
  for (int j = 0; j < 8; ++j) h1[j] = f2bf(Lt[kc + 8 + j][n]);
  unsigned short* dst = Wt + (size_t)(c0 + n) * 1024 + k0 + kc;
  *(ushort8v*)dst = h0;
  *(ushort8v*)(dst + 8) = h1;
}

// ---------------------------------------------------------------------------
// Kernel 1: QKV GEMM, 128m x 256n tile, BK=32, 8 waves (2m x 4n), dbuf LDS.
// ---------------------------------------------------------------------------
__global__ __launch_bounds__(512) void qkv_gemm2(
    const float* __restrict__ x, const unsigned short* __restrict__ Wt,
    const float* __restrict__ bq, const float* __restrict__ bk,
    const float* __restrict__ bv, unsigned short* __restrict__ qkv)
{
  __shared__ __align__(16) unsigned short Ab[2][4096];   // [128][32] bf16
  __shared__ __align__(16) unsigned short Bb[2][8192];   // [256][32] bf16
  const int tid = threadIdx.x;
  const int lane = tid & 63, wid = tid >> 6;
  const int l15 = lane & 15, l4 = lane >> 4;

  const int id = blockIdx.x;
  const int swz = (id & 7) * 192 + (id >> 3);
  const int m0 = (swz / 12) * 128, n0 = (swz % 12) * 256;
  const int wm = (wid >> 2) * 64, wn = (wid & 3) * 64;

  const int arow = tid >> 2, akb = (tid & 3) * 16;
  const int brow1 = wid * 16 + (lane >> 2), bkb = (lane & 3) * 16;
  const float* Abase = x + (size_t)(m0 + arow) * 1024 + (akb >> 1);
  const char* Bg1 = (const char*)Wt + (size_t)(n0 + brow1) * 2048 + bkb;
  const char* Bg2 = Bg1 + 128 * 2048;

  f32x4 acc[4][4] = {};

#define QSTAGE(t, b) do {                                                    \
    float4v f0 = *(const float4v*)(Abase + (t) * 32);                        \
    float4v f1 = *(const float4v*)(Abase + (t) * 32 + 4);                    \
    gload_lds16(Bg1 + (t) * 64, (char*)&Bb[b][0] + wid * 1024);              \
    gload_lds16(Bg2 + (t) * 64, (char*)&Bb[b][0] + 8192 + wid * 1024);       \
    ushort8v hv;                                                             \
    hv[0] = f2bf(f0[0]); hv[1] = f2bf(f0[1]);                                \
    hv[2] = f2bf(f0[2]); hv[3] = f2bf(f0[3]);                                \
    hv[4] = f2bf(f1[0]); hv[5] = f2bf(f1[1]);                                \
    hv[6] = f2bf(f1[2]); hv[7] = f2bf(f1[3]);                                \
    *(ushort8v*)((char*)&Ab[b][0] + tid * 16) = hv;                          \
  } while (0)

  QSTAGE(0, 0);
  __syncthreads();

  for (int t = 0; t < 32; ++t) {
    const int cur = t & 1;
    if (t < 31) QSTAGE(t + 1, cur ^ 1);
    short8v a[4], b[4];
    #pragma unroll
    for (int mf = 0; mf < 4; ++mf)
      a[mf] = *(const short8v*)((const char*)&Ab[cur][0] +
                                (wm + mf * 16 + l15) * 64 + l4 * 16);
    #pragma unroll
    for (int nf = 0; nf < 4; ++nf)
      b[nf] = *(const short8v*)((const char*)&Bb[cur][0] +
                                (wn + nf * 16 + l15) * 64 + l4 * 16);
    #pragma unroll
    for (int mf = 0; mf < 4; ++mf)
      #pragma unroll
      for (int nf = 0; nf < 4; ++nf)
        acc[mf][nf] = __builtin_amdgcn_mfma_f32_16x16x32_bf16(a[mf], b[nf], acc[mf][nf], 0, 0, 0);
    __syncthreads();
  }
#undef QSTAGE

  const int wsel = n0 >> 10;
  const float* bias = (wsel == 0) ? bq : (wsel == 1) ? bk : bv;
  const float scale = (wsel == 0) ? 0.0625f : 1.0f;
  unsigned short* dst = qkv + (size_t)wsel * QSZ;
  #pragma unroll
  for (int nf = 0; nf < 4; ++nf) {
    int ncol = n0 + wn + nf * 16 + l15;
    int ncl = ncol & 1023;
    float bv_ = bias[ncl];
    int h = ncl >> 8, d = ncl & 255;
    #pragma unroll
    for (int mf = 0; mf < 4; ++mf)
      #pragma unroll
      for (int e = 0; e < 4; ++e) {
        int mrow = m0 + wm + mf * 16 + l4 * 4 + e;
        int bb = mrow >> 11, nn = mrow & 2047;
        dst[((size_t)(bb * 4 + h) * 2048 + nn) * 256 + d] =
            f2bf((acc[mf][nf][e] + bv_) * scale);
      }
  }
}

// ---------------------------------------------------------------------------
// Kernel 2: flash attention.  4 waves x 32 q-rows, KVBLK=32, dbuf.
//  - K reg-staged: row-major [32][256] with MFMA k-order pre-permuted and
//    XOR swizzle (byte ^= (kv&7)<<4) -> QK^T A-frag = one conflict-free
//    ds_read_b128.
//  - V staged via global_load_lds, subtiled [D=16][kv=32][16d]; PV uses
//    ds_read_b64_tr_b16 in depth-4 pipelined groups (lgkmcnt(8)).
// Output written in place over the block's own Q rows.
// ---------------------------------------------------------------------------
__global__ __launch_bounds__(256) void attn_fused(
    unsigned short* __restrict__ qkv)
{
  __shared__ __align__(16) unsigned short Kbuf[2][8192];   // 16 KB each
  __shared__ __align__(16) unsigned short Vbuf[2][8192];   // 16 KB each
  const int tid = threadIdx.x;
  const int lane = tid & 63, wid = tid >> 6;
  const int l15 = lane & 15, l4 = lane >> 4;

  const int id0 = blockIdx.x;                 // 0..511
  const int swzb = (id0 & 7) * 64 + (id0 >> 3);
  const int qt = swzb & 15, bh = swzb >> 4;

  const unsigned short* Qh = qkv + (size_t)bh * (N_ * DH);
  const unsigned short* Kh = qkv + (size_t)QSZ + (size_t)bh * (N_ * DH);
  const unsigned short* Vh = qkv + (size_t)2 * QSZ + (size_t)bh * (N_ * DH);

  // Q fragments: 2 q-groups x 8 k-steps (32 q-rows per wave)
  const int q0 = qt * 128 + wid * 32;
  short8v qf0[8], qf1[8];
  #pragma unroll
  for (int ks = 0; ks < 8; ++ks) {
    const unsigned short* p0 = Qh + (size_t)(q0 + l15) * DH + ks * 32 + l4 * 4;
    const unsigned short* p1 = p0 + 16 * DH;
    qf0[ks] = pack8(*(const short4v*)p0, *(const short4v*)(p0 + 16));
    qf1[ks] = pack8(*(const short4v*)p1, *(const short4v*)(p1 + 16));
  }

  // K staging: thread handles kv=tid>>3, k-group ks=tid&7 (32 elems, 64 B)
  const int skv = tid >> 3, sks = tid & 7;
  const unsigned short* Kg = Kh + (size_t)skv * DH + sks * 32;
  int kdst[4];
  #pragma unroll
  for (int g = 0; g < 4; ++g)
    kdst[g] = (skv * 512 + sks * 64 + g * 16) ^ ((skv & 7) << 4);

  // V staging: 4 gload chunks per thread
  int vgoff[4];
  #pragma unroll
  for (int r = 0; r < 4; ++r)
    vgoff[r] = (lane >> 1) * 512 + (r * 4 + wid) * 32 + (lane & 1) * 16;

  f32x4 ot0[16] = {}, ot1[16] = {};
  float m0r = -1.0e30f, m1r = -1.0e30f, l0r = 0.0f, l1r = 0.0f;

  ushort8v kin0, kin1, kin2, kin3;

#define KISSUE(t) do {                                                       \
    const unsigned short* kp = Kg + (size_t)(t) * (32 * DH);                 \
    kin0 = *(const ushort8v*)(kp);                                           \
    kin1 = *(const ushort8v*)(kp + 8);                                       \
    kin2 = *(const ushort8v*)(kp + 16);                                      \
    kin3 = *(const ushort8v*)(kp + 24);                                      \
  } while (0)

#define KWRITE(b) do {                                                       \
    char* kb = (char*)&Kbuf[b][0];                                           \
    *(ushort8v*)(kb + kdst[0]) = umk8(ulo4(kin0), ulo4(kin2));               \
    *(ushort8v*)(kb + kdst[1]) = umk8(uhi4(kin0), uhi4(kin2));               \
    *(ushort8v*)(kb + kdst[2]) = umk8(ulo4(kin1), ulo4(kin3));               \
    *(ushort8v*)(kb + kdst[3]) = umk8(uhi4(kin1), uhi4(kin3));               \
  } while (0)

#define VISSUE(t, b) do {                                                    \
    const char* vg = (const char*)Vh + (size_t)(t) * 16384;                  \
    _Pragma("unroll")                                                        \
    for (int r = 0; r < 4; ++r)                                              \
      gload_lds16(vg + vgoff[r], (char*)&Vbuf[b][0] + r * 4096 + wid * 1024);\
  } while (0)

#define TR2(d0v, d1v, dfp) do {                                              \
    unsigned ab = vb + (unsigned)(dfp) * 1024u;                              \
    asm volatile("ds_read_b64_tr_b16 %0, %1" : "=v"(d0v) : "v"(ab));         \
    asm volatile("ds_read_b64_tr_b16 %0, %1" : "=v"(d1v) : "v"(ab + 512u));  \
  } while (0)

#define PVG(R0,R1,R2,R3,R4,R5,R6,R7, N0,N1,N2,N3,N4,N5,N6,N7, g, last) do {  \
    if (!(last)) {                                                           \
      TR2(N0, N1, 4 * (g) + 4); TR2(N2, N3, 4 * (g) + 5);                    \
      TR2(N4, N5, 4 * (g) + 6); TR2(N6, N7, 4 * (g) + 7);                    \
      asm volatile("s_waitcnt lgkmcnt(8)" ::: "memory");                     \
    } else {                                                                 \
      asm volatile("s_waitcnt lgkmcnt(0)" ::: "memory");                     \
    }                                                                        \
    __builtin_amdgcn_sched_barrier(0);                                       \
    __builtin_amdgcn_s_setprio(1);                                           \
    ot0[4*(g)+0] = __builtin_amdgcn_mfma_f32_16x16x32_bf16(pack8(R0,R1), pb0, ot0[4*(g)+0], 0,0,0); \
    ot1[4*(g)+0] = __builtin_amdgcn_mfma_f32_16x16x32_bf16(pack8(R0,R1), pb1, ot1[4*(g)+0], 0,0,0); \
    ot0[4*(g)+1] = __builtin_amdgcn_mfma_f32_16x16x32_bf16(pack8(R2,R3), pb0, ot0[4*(g)+1], 0,0,0); \
    ot1[4*(g)+1] = __builtin_amdgcn_mfma_f32_16x16x32_bf16(pack8(R2,R3), pb1, ot1[4*(g)+1], 0,0,0); \
    ot0[4*(g)+2] = __builtin_amdgcn_mfma_f32_16x16x32_bf16(pack8(R4,R5), pb0, ot0[4*(g)+2], 0,0,0); \
    ot1[4*(g)+2] = __builtin_amdgcn_mfma_f32_16x16x32_bf16(pack8(R4,R5), pb1, ot1[4*(g)+2], 0,0,0); \
    ot0[4*(g)+3] = __builtin_amdgcn_mfma_f32_16x16x32_bf16(pack8(R6,R7), pb0, ot0[4*(g)+3], 0,0,0); \
    ot1[4*(g)+3] = __builtin_amdgcn_mfma_f32_16x16x32_bf16(pack8(R6,R7), pb1, ot1[4*(g)+3], 0,0,0); \
    __builtin_amdgcn_s_setprio(0);                                           \
  } while (0)

  // prologue: stage tile 0
  KISSUE(0);
  VISSUE(0, 0);
  KWRITE(0);
  __syncthreads();

  for (int t = 0; t < 64; ++t) {
    const int cur = t & 1;
    if (t < 63) { KISSUE(t + 1); VISSUE(t + 1, cur ^ 1); }

    // ---- QK^T: S^T = K . Q^T ----
    const char* Kc = (const char*)&Kbuf[cur][0];
    const int swzk = (l15 & 7) << 4;
    f32x4 st00 = {0,0,0,0}, st01 = {0,0,0,0}, st10 = {0,0,0,0}, st11 = {0,0,0,0};
    __builtin_amdgcn_s_setprio(1);
    #pragma unroll
    for (int ks = 0; ks < 8; ++ks) {
      int o = (ks * 64 + l4 * 16) ^ swzk;
      short8v af0 = *(const short8v*)(Kc + l15 * 512 + o);
      short8v af1 = *(const short8v*)(Kc + (16 + l15) * 512 + o);
      st00 = __builtin_amdgcn_mfma_f32_16x16x32_bf16(af0, qf0[ks], st00, 0, 0, 0);
      st01 = __builtin_amdgcn_mfma_f32_16x16x32_bf16(af0, qf1[ks], st01, 0, 0, 0);
      st10 = __builtin_amdgcn_mfma_f32_16x16x32_bf16(af1, qf0[ks], st10, 0, 0, 0);
      st11 = __builtin_amdgcn_mfma_f32_16x16x32_bf16(af1, qf1[ks], st11, 0, 0, 0);
    }
    __builtin_amdgcn_s_setprio(0);

    // K(t+1) -> LDS alt buffer (no barrier needed: different buffer)
    if (t < 63) KWRITE(cur ^ 1);

    // ---- online softmax with defer-max (THR = 8) ----
    short8v pb0, pb1;
    {
      float tmax = fmaxf(fmaxf(st00[0], st00[1]), fmaxf(st00[2], st00[3]));
      tmax = fmaxf(tmax, fmaxf(fmaxf(st10[0], st10[1]), fmaxf(st10[2], st10[3])));
      tmax = fmaxf(tmax, __shfl_xor(tmax, 16));
      tmax = fmaxf(tmax, __shfl_xor(tmax, 32));
      if (__any(tmax > m0r + 8.0f)) {
        float mn = fmaxf(m0r, tmax), al = __expf(m0r - mn);
        l0r *= al;
        #pragma unroll
        for (int df = 0; df < 16; ++df) ot0[df] *= al;
        m0r = mn;
      }
      float psum = 0.0f;
      #pragma unroll
      for (int e = 0; e < 4; ++e) {
        float p0 = __expf(st00[e] - m0r), p1 = __expf(st10[e] - m0r);
        pb0[e] = (short)f2bf(p0); pb0[e + 4] = (short)f2bf(p1);
        psum += p0 + p1;
      }
      psum += __shfl_xor(psum, 16);
      psum += __shfl_xor(psum, 32);
      l0r += psum;
    }
    {
      float tmax = fmaxf(fmaxf(st01[0], st01[1]), fmaxf(st01[2], st01[3]));
      tmax = fmaxf(tmax, fmaxf(fmaxf(st11[0], st11[1]), fmaxf(st11[2], st11[3])));
      tmax = fmaxf(tmax, __shfl_xor(tmax, 16));
      tmax = fmaxf(tmax, __shfl_xor(tmax, 32));
      if (__any(tmax > m1r + 8.0f)) {
        float mn = fmaxf(m1r, tmax), al = __expf(m1r - mn);
        l1r *= al;
        #pragma unroll
        for (int df = 0; df < 16; ++df) ot1[df] *= al;
        m1r = mn;
      }
      float psum = 0.0f;
      #pragma unroll
      for (int e = 0; e < 4; ++e) {
        float p0 = __expf(st01[e] - m1r), p1 = __expf(st11[e] - m1r);
        pb1[e] = (short)f2bf(p0); pb1[e + 4] = (short)f2bf(p1);
        psum += p0 + p1;
      }
      psum += __shfl_xor(psum, 16);
      psum += __shfl_xor(psum, 32);
      l1r += psum;
    }

    // ---- PV: O^T += V^T . P^T, depth-4 pipelined tr_reads ----
    const unsigned vb = (unsigned)(uintptr_t)(&Vbuf[cur][0]) + lane * 8;
    short4v A0,A1,A2,A3,A4,A5,A6,A7, B0,B1,B2,B3,B4,B5,B6,B7;
    TR2(A0, A1, 0); TR2(A2, A3, 1); TR2(A4, A5, 2); TR2(A6, A7, 3);
    PVG(A0,A1,A2,A3,A4,A5,A6,A7, B0,B1,B2,B3,B4,B5,B6,B7, 0, 0);
    PVG(B0,B1,B2,B3,B4,B5,B6,B7, A0,A1,A2,A3,A4,A5,A6,A7, 1, 0);
    PVG(A0,A1,A2,A3,A4,A5,A6,A7, B0,B1,B2,B3,B4,B5,B6,B7, 2, 0);
    PVG(B0,B1,B2,B3,B4,B5,B6,B7, A0,A1,A2,A3,A4,A5,A6,A7, 3, 1);

    __syncthreads();   // drains vmcnt/lgkm: V(t+1), K writes visible
  }

  // ---- epilogue: normalize, overwrite own Q rows ([B,H,N,DH]) ----
  unsigned short* Oq = (unsigned short*)Qh;
  {
    float inv = 1.0f / l0r;
    size_t base = (size_t)(q0 + l15) * DH;
    #pragma unroll
    for (int df = 0; df < 16; ++df) {
      ushort4v o;
      #pragma unroll
      for (int e = 0; e < 4; ++e) o[e] = f2bf(ot0[df][e] * inv);
      *(ushort4v*)&Oq[base + df * 16 + l4 * 4] = o;
    }
  }
  {
    float inv = 1.0f / l1r;
    size_t base = (size_t)(q0 + 16 + l15) * DH;
    #pragma unroll
    for (int df = 0; df < 16; ++df) {
      ushort4v o;
      #pragma unroll
      for (int e = 0; e < 4; ++e) o[e] = f2bf(ot1[df][e] * inv);
      *(ushort4v*)&Oq[base + df * 16 + l4 * 4] = o;
    }
  }
#undef KISSUE
#undef KWRITE
#undef VISSUE
#undef TR2
#undef PVG
}

// ---------------------------------------------------------------------------
// Kernel 3: out[16384][256] = attnO @ Wo + bo.  attnO is in the Q region,
// layout [B,H,N,DH]; logical row m = bb*2048+q, col k = h*256+d.
// ---------------------------------------------------------------------------
__global__ __launch_bounds__(512) void out_gemm2(
    const unsigned short* __restrict__ Aq, const unsigned short* __restrict__ WoT,
    const float* __restrict__ bo, float* __restrict__ out)
{
  __shared__ __align__(16) unsigned short Ab[2][4096];
  __shared__ __align__(16) unsigned short Bb[2][8192];
  const int tid = threadIdx.x;
  const int lane = tid & 63, wid = tid >> 6;
  const int l15 = lane & 15, l4 = lane >> 4;
  const int m0 = blockIdx.x * 128;
  const int wm = (wid >> 2) * 64, wn = (wid & 3) * 64;

  const int arow = wid * 16 + (lane >> 2), akb = (lane & 3) * 16;
  const int bb = m0 >> 11;
  const int qrow = (m0 & 2047) + arow;
  const char* Bg1 = (const char*)WoT + (size_t)arow * 2048 + akb;
  const char* Bg2 = Bg1 + 128 * 2048;

  f32x4 acc[4][4] = {};

#define OSTAGE(t, b) do {                                                    \
    int h = (t) >> 3, d0 = (((t) & 7) * 32) + (akb >> 1);                    \
    gload_lds16(Aq + ((size_t)(bb * 4 + h) * 2048 + qrow) * 256 + d0,        \
                (char*)&Ab[b][0] + wid * 1024);                              \
    gload_lds16(Bg1 + (t) * 64, (char*)&Bb[b][0] + wid * 1024);              \
    gload_lds16(Bg2 + (t) * 64, (char*)&Bb[b][0] + 8192 + wid * 1024);       \
  } while (0)

  OSTAGE(0, 0);
  __syncthreads();

  for (int t = 0; t < 32; ++t) {
    const int cur = t & 1;
    if (t < 31) OSTAGE(t + 1, cur ^ 1);
    short8v a[4], b[4];
    #pragma unroll
    for (int mf = 0; mf < 4; ++mf)
      a[mf] = *(const short8v*)((const char*)&Ab[cur][0] +
                                (wm + mf * 16 + l15) * 64 + l4 * 16);
    #pragma unroll
    for (int nf = 0; nf < 4; ++nf)
      b[nf] = *(const short8v*)((const char*)&Bb[cur][0] +
                                (wn + nf * 16 + l15) * 64 + l4 * 16);
    #pragma unroll
    for (int mf = 0; mf < 4; ++mf)
      #pragma unroll
      for (int nf = 0; nf < 4; ++nf)
        acc[mf][nf] = __builtin_amdgcn_mfma_f32_16x16x32_bf16(a[mf], b[nf], acc[mf][nf], 0, 0, 0);
    __syncthreads();
  }
#undef OSTAGE

  #pragma unroll
  for (int nf = 0; nf < 4; ++nf) {
    int ncol = wn + nf * 16 + l15;
    float bv_ = bo[ncol];
    #pragma unroll
    for (int mf = 0; mf < 4; ++mf)
      #pragma unroll
      for (int e = 0; e < 4; ++e) {
        int mrow = m0 + wm + mf * 16 + l4 * 4 + e;
        out[(size_t)mrow * 256 + ncol] = acc[mf][nf][e] + bv_;
      }
  }
}

// ---------------------------------------------------------------------------
extern "C" void kernel_launch(void* const* d_in, const int* in_sizes, int n_in,
                              void* d_out, int out_size, void* d_ws, size_t ws_size,
                              hipStream_t stream) {
  const float* x  = (const float*)d_in[0];
  const float* Wq = (const float*)d_in[1];
  const float* bq = (const float*)d_in[2];
  const float* Wk = (const float*)d_in[3];
  const float* bk = (const float*)d_in[4];
  const float* Wv = (const float*)d_in[5];
  const float* bv = (const float*)d_in[6];
  const float* Wo = (const float*)d_in[7];
  const float* bo = (const float*)d_in[8];

  unsigned short* qkvbuf = (unsigned short*)d_ws;       // Q|K|V bf16 (96 MiB)
  unsigned short* Wt     = qkvbuf + (size_t)3 * QSZ;    // [3328][1024] bf16
  float* out = (float*)d_out;

  prep_wt  <<<dim3(52, 16), 256, 0, stream>>>(Wq, Wk, Wv, Wo, Wt);
  qkv_gemm2<<<dim3(1536),   512, 0, stream>>>(x, Wt, bq, bk, bv, qkvbuf);
  attn_fused<<<dim3(512),   256, 0, stream>>>(qkvbuf);
  out_gemm2<<<dim3(128),    512, 0, stream>>>(qkvbuf, Wt + (size_t)3072 * 1024, bo, out);
}